// Round 2
// baseline (3705.223 us; speedup 1.0000x reference)
//
#include <hip/hip_runtime.h>
#include <hip/hip_bf16.h>

#define D 128
typedef __hip_bfloat16 bf16;
typedef __hip_bfloat162 bf162;

// ================= dtype probes =================
// flags[0]: 1 if float inputs are f32, 0 if bf16
// flags[1]: 1 if edge_index is int64, 0 if int32
__global__ void probe_float_kernel(const void* __restrict__ x, int* __restrict__ flags) {
    __shared__ int cnt;
    if (threadIdx.x == 0) cnt = 0;
    __syncthreads();
    const unsigned short* u = (const unsigned short*)x;
    int bad = 0;
    // low 16 bits of each 32-bit word: valid bf16 (element 2i) if data is bf16,
    // mantissa junk if data is f32
    for (int i = threadIdx.x; i < 2048; i += blockDim.x) {
        unsigned short v = u[2 * i];
        int e = (v >> 7) & 0xFF;
        if (e == 255 || (e != 0 && (e < 90 || e > 165))) bad++;
    }
    atomicAdd(&cnt, bad);
    __syncthreads();
    if (threadIdx.x == 0) flags[0] = (cnt > 256) ? 1 : 0;
}

__global__ void probe_int_kernel(const void* __restrict__ ei, int* __restrict__ flags) {
    __shared__ int cnt;
    if (threadIdx.x == 0) cnt = 0;
    __syncthreads();
    const int* w = (const int*)ei;
    int nz = 0;
    // odd 32-bit words are all zero iff data is int64 (values < 2^31, nonneg)
    for (int i = threadIdx.x; i < 512; i += blockDim.x) {
        if (w[2 * i + 1] != 0) nz++;
    }
    atomicAdd(&cnt, nz);
    __syncthreads();
    if (threadIdx.x == 0) flags[1] = (cnt == 0) ? 1 : 0;
}

// ================= diagnostic spins (read duration in rocprof next round) ==
// long (~100us) if flags[which]==1, short (~3us) if 0
__global__ void diag_flag_float_spin(const int* flags, float* sink) {
    int iters = flags[0] ? 60000 : 2000;
    float v = (float)threadIdx.x;
    for (int i = 0; i < iters; ++i) v = fmaf(v, 1.0000001f, 0.5f);
    if (v == 1.2345e30f) sink[0] = v;
}
__global__ void diag_flag_int_spin(const int* flags, float* sink) {
    int iters = flags[1] ? 60000 : 2000;
    float v = (float)threadIdx.x;
    for (int i = 0; i < iters; ++i) v = fmaf(v, 1.0000001f, 0.5f);
    if (v == 1.2345e30f) sink[0] = v;
}
// duration ~ 1us per MB of ws_size (capped 256MB)
__global__ void diag_ws_spin(int iters, float* sink) {
    float v = (float)threadIdx.x;
    for (int i = 0; i < iters; ++i) v = fmaf(v, 1.0000001f, 0.5f);
    if (v == 1.2345e30f) sink[0] = v;
}

// ================= helpers =================
__device__ __forceinline__ int load_idx(const void* ei, long long pos, int is64) {
    if (is64) return (int)((const long long*)ei)[pos];
    return ((const int*)ei)[pos];
}

// ================= degree =================
__global__ void degree_kernel(const void* __restrict__ ei, float* __restrict__ deg,
                              int E, const int* __restrict__ flags) {
    int e = blockIdx.x * blockDim.x + threadIdx.x;
    if (e >= E) return;
    int c = load_idx(ei, (long long)E + e, flags[1]);  // col = dest
    atomicAdd(&deg[c], 1.0f);
}

__global__ void dinv_kernel(const float* __restrict__ deg, float* __restrict__ dinv, int n) {
    int i = blockIdx.x * blockDim.x + threadIdx.x;
    if (i < n) dinv[i] = rsqrtf(deg[i] + 1.0f);
}

// ================= h = x @ W, stored as bf16 =================
// f32 path:  h -> ws buf0 (bf16), acc will be d_out (f32)
// bf16 path: h -> d_out (bf16), acc will be ws buf0 (f32)
__global__ void gemm_kernel(const void* __restrict__ x, const void* __restrict__ W,
                            void* d_out, float* buf0, const int* __restrict__ flags) {
    __shared__ float xs[D];
    const int r = blockIdx.x;
    const int t = threadIdx.x;  // 0..63
    const int f = flags[0];

    if (f) {  // f32 inputs
        const float2* xr = (const float2*)((const float*)x + (size_t)r * D);
        float2 v = xr[t];
        xs[2 * t] = v.x; xs[2 * t + 1] = v.y;
    } else {
        const bf162* xr = (const bf162*)((const bf16*)x + (size_t)r * D);
        bf162 v = xr[t];
        xs[2 * t] = __bfloat162float(v.x); xs[2 * t + 1] = __bfloat162float(v.y);
    }
    __syncthreads();

    float a0 = 0.f, a1 = 0.f;
    if (f) {
        const float2* W2 = (const float2*)W;
#pragma unroll 8
        for (int k = 0; k < D; ++k) {
            float xk = xs[k];
            float2 wb = W2[k * 64 + t];
            a0 += xk * wb.x; a1 += xk * wb.y;
        }
    } else {
        const bf162* W2 = (const bf162*)W;
#pragma unroll 8
        for (int k = 0; k < D; ++k) {
            float xk = xs[k];
            bf162 wb = W2[k * 64 + t];
            a0 += xk * __bfloat162float(wb.x); a1 += xk * __bfloat162float(wb.y);
        }
    }
    bf16* hdst = f ? (bf16*)buf0 : (bf16*)d_out;
    bf162* hp = (bf162*)hdst;
    bf162 o; o.x = __float2bfloat16(a0); o.y = __float2bfloat16(a1);
    hp[(size_t)r * 64 + t] = o;
}

// ================= acc[i] = dinv^2 * h[i] (self loop, non-atomic init) =====
__global__ void self_init_kernel(float* buf0, void* d_out, const float* __restrict__ dinv,
                                 int total, const int* __restrict__ flags) {
    int gid = blockIdx.x * blockDim.x + threadIdx.x;
    if (gid >= total) return;
    const int f = flags[0];
    const bf16* h = f ? (const bf16*)buf0 : (const bf16*)d_out;
    float* acc = f ? (float*)d_out : buf0;
    float dv = dinv[gid >> 7];
    acc[gid] = dv * dv * __bfloat162float(h[gid]);
}

// ================= edge scatter: acc[col] += norm * h[row] =================
__global__ void scatter_kernel(const void* __restrict__ ei, const float* __restrict__ dinv,
                               float* buf0, void* d_out, int E, const int* __restrict__ flags) {
    int e = blockIdx.x * 2 + (threadIdx.x >> 7);
    int c = threadIdx.x & (D - 1);
    if (e >= E) return;
    const int f = flags[0];
    const int i64 = flags[1];
    int s = load_idx(ei, e, i64);
    int d = load_idx(ei, (long long)E + e, i64);
    const bf16* h = f ? (const bf16*)buf0 : (const bf16*)d_out;
    float* acc = f ? (float*)d_out : buf0;
    float nrm = dinv[s] * dinv[d];
    float v = nrm * __bfloat162float(h[(size_t)s * D + c]);
    atomicAdd(&acc[(size_t)d * D + c], v);
}

// ================= out = acc + b =================
__global__ void finalize_kernel(float* buf0, const void* __restrict__ b, void* d_out,
                                int total, const int* __restrict__ flags) {
    int gid = blockIdx.x * blockDim.x + threadIdx.x;
    if (gid >= total) return;
    const int f = flags[0];
    const int c = gid & (D - 1);
    if (f) {
        float* acc = (float*)d_out;
        float bias = ((const float*)b)[c];
        acc[gid] = acc[gid] + bias;  // in-place, output stays f32
    } else {
        float v = buf0[gid] + __bfloat162float(((const bf16*)b)[c]);
        ((bf16*)d_out)[gid] = __float2bfloat16(v);
    }
}

extern "C" void kernel_launch(void* const* d_in, const int* in_sizes, int n_in,
                              void* d_out, int out_size, void* d_ws, size_t ws_size,
                              hipStream_t stream) {
    const void* x = d_in[0];
    const void* ei = d_in[1];
    const void* W = d_in[2];
    const void* b = d_in[3];

    const int n = in_sizes[0] / D;   // 50000
    const int E = in_sizes[1] / 2;   // 600000

    // ws layout: [buf0: N*D f32 = 25.6MB][deg: N f32][dinv: N f32][flags: 2 int][sink]
    float* buf0 = (float*)d_ws;
    float* deg  = buf0 + (size_t)n * D;
    float* dinv = deg + n;
    int* flags  = (int*)(dinv + n);
    float* sink = (float*)(flags + 2);

    probe_float_kernel<<<1, 256, 0, stream>>>(x, flags);
    probe_int_kernel<<<1, 256, 0, stream>>>(ei, flags);

    // diagnostics: durations visible in rocprof dispatch table
    diag_flag_float_spin<<<1, 64, 0, stream>>>(flags, sink);
    diag_flag_int_spin<<<1, 64, 0, stream>>>(flags, sink);
    int ws_mb = (int)(ws_size >> 20); if (ws_mb > 256) ws_mb = 256;
    diag_ws_spin<<<1, 64, 0, stream>>>(ws_mb * 600, sink);

    hipMemsetAsync(deg, 0, (size_t)n * sizeof(float), stream);
    degree_kernel<<<(E + 255) / 256, 256, 0, stream>>>(ei, deg, E, flags);
    dinv_kernel<<<(n + 255) / 256, 256, 0, stream>>>(deg, dinv, n);
    gemm_kernel<<<n, 64, 0, stream>>>(x, W, d_out, buf0, flags);
    self_init_kernel<<<(n * D + 255) / 256, 256, 0, stream>>>(buf0, d_out, dinv, n * D, flags);
    scatter_kernel<<<(E + 1) / 2, 256, 0, stream>>>(ei, dinv, buf0, d_out, E, flags);
    finalize_kernel<<<(n * D + 255) / 256, 256, 0, stream>>>(buf0, b, d_out, n * D, flags);
}